// Round 2
// baseline (162.542 us; speedup 1.0000x reference)
//
#include <hip/hip_runtime.h>

// Problem constants (fixed by the reference).
#define N_SPK 1024
#define M_UTT 32
#define D_EMB 512
#define NROWS (N_SPK * M_UTT)   // 32768

#define NEG_INF (-__builtin_inff())
#define MARGIN 25.0f   // skip row iff dgl - rowbound >= MARGIN (err < 1.4e-8/row)

using f32x4 = __attribute__((ext_vector_type(4))) float;

// ===========================================================================
// FAST PATH (round 12): prune-then-compute, now 3 dispatches (was 4).
//
// Math unchanged from R10: dgl ≈ 2641 ± 630 while every off-diag logit is
// bounded by |w|·||e||·max||c|| + b ≈ 459 (Cauchy-Schwarz).  Rows with
// dgl - bound >= 25 nats contribute exactly-0 loss in the reference too.
// Survivors (~10 rows) get an exact fp32 1024-logit max-carrying logsumexp.
//
// R12 change (dispatch-structure, not math):
//  - active_kernel + merge_kernel fused into row_kernel: one block per
//    surviving row computes all 1024 logits (4 speakers/thread), reduces
//    with the IDENTICAL arithmetic tree as the old per-chunk partials +
//    merge combine (bit-exact, absmax stays 0.0), and atomicAdds the row
//    loss directly.  -1 graph node, -1 dispatch gap, -merge exec.
// R11 kept: no init dispatch (prep block 0 zeroes out/count); c2A
// per-speaker array instead of device atomicMax.
// R8 lesson kept: no device-scope __threadfence in wide kernels; all
// cross-kernel deps go through dispatch boundaries (same stream).
// ===========================================================================

// ---------------------------------------------------------------------------
// prep: one block per speaker n (32 rows x 512 dims).  Reads e ONCE.
//  - sumf[n*512+d] = sum_m e[n][m][d]      (fp32 speaker sum, 2 MB)
//  - ssqA[row]     = ||e_row||^2
//  - dgl[row]      = w*(e.sum + ||e||^2/31) + b   (exact fp32 diag logit)
//  - c2A[n]        = ||c_n||^2             (per-speaker, no atomics)
//  - block 0 zeroes out[0] and *count (replaces init dispatch)
// Row data retained in registers across the centroid barrier (R7-verified).
// ---------------------------------------------------------------------------
__global__ __launch_bounds__(256)
void prep_kernel(const float* __restrict__ e,
                 float* __restrict__ sumf, float* __restrict__ ssqA,
                 float* __restrict__ dgl, float* __restrict__ c2A,
                 const float* __restrict__ wp, const float* __restrict__ bp,
                 float* __restrict__ out, int* __restrict__ count) {
    __shared__ float csum[4][D_EMB];   // 8 KiB
    __shared__ float c2red[4];
    const int n = blockIdx.x;
    const int wv = threadIdx.x >> 6, l = threadIdx.x & 63;

    if (n == 0 && threadIdx.x == 0) { out[0] = 0.f; *count = 0; }

    float xs[8][8];     // retained row data (lane's 8 dims x 8 rows)
    float ssq[8];       // per-row ||e||^2 (wave-uniform after butterfly)
    float cacc[8];
#pragma unroll
    for (int j = 0; j < 8; ++j) cacc[j] = 0.f;

#pragma unroll
    for (int mi = 0; mi < 8; ++mi) {
        const int m = mi * 4 + wv;
        const size_t row = (size_t)n * M_UTT + m;
        const float* p = e + row * D_EMB + l * 8;
        float4 x0 = *(const float4*)p;
        float4 x1 = *(const float4*)(p + 4);
        xs[mi][0] = x0.x; xs[mi][1] = x0.y; xs[mi][2] = x0.z; xs[mi][3] = x0.w;
        xs[mi][4] = x1.x; xs[mi][5] = x1.y; xs[mi][6] = x1.z; xs[mi][7] = x1.w;
        float sq = 0.f;
#pragma unroll
        for (int j = 0; j < 8; ++j) {
            float x = xs[mi][j];
            cacc[j] += x;
            sq = __builtin_fmaf(x, x, sq);
        }
#pragma unroll
        for (int off = 32; off; off >>= 1) sq += __shfl_xor(sq, off);
        ssq[mi] = sq;
        if (l == 0) ssqA[row] = sq;
    }

#pragma unroll
    for (int j = 0; j < 8; ++j) csum[wv][l * 8 + j] = cacc[j];
    __syncthreads();
    float c2acc = 0.f;
    for (int d = threadIdx.x; d < D_EMB; d += 256) {
        float s = csum[0][d] + csum[1][d] + csum[2][d] + csum[3][d];
        csum[0][d] = s;                               // full speaker sum
        sumf[(size_t)n * D_EMB + d] = s;
        float c = s * (1.0f / M_UTT);
        c2acc = __builtin_fmaf(c, c, c2acc);
    }
#pragma unroll
    for (int off = 32; off; off >>= 1) c2acc += __shfl_xor(c2acc, off);
    if (l == 0) c2red[wv] = c2acc;
    __syncthreads();   // csum[0] full sums + c2red visible
    if (threadIdx.x == 0)
        c2A[n] = (c2red[0] + c2red[1]) + (c2red[2] + c2red[3]);

    // Exact fp32 diag: dgl[row] = w*(e.sum + ssq/31) + b.
    float sv[8];
#pragma unroll
    for (int j = 0; j < 8; ++j) sv[j] = csum[0][l * 8 + j];
    const float w = wp[0], bb = bp[0];
#pragma unroll
    for (int mi = 0; mi < 8; ++mi) {
        float dg = 0.f;
#pragma unroll
        for (int j = 0; j < 8; ++j) dg = __builtin_fmaf(xs[mi][j], sv[j], dg);
#pragma unroll
        for (int off = 32; off; off >>= 1) dg += __shfl_xor(dg, off);
        if (l == 0) {
            const size_t row = (size_t)n * M_UTT + mi * 4 + wv;
            dgl[row] = __builtin_fmaf(w, dg + ssq[mi] * (1.0f / 31.0f), bb);
        }
    }
}

// ---------------------------------------------------------------------------
// select: one thread per row.  Each block first max-reduces c2A (4 KB,
// L2-hot) to Cmax^2 — exact same max the old atomicMax produced.  Row
// survives iff dgl - (|w|*||e||*Cmax + b) < MARGIN.  Survivors appended to
// active[] (device atomic; ~10 appends total).
// ---------------------------------------------------------------------------
__global__ __launch_bounds__(256)
void select_kernel(const float* __restrict__ ssqA, const float* __restrict__ dgl,
                   const float* __restrict__ c2A,
                   const float* __restrict__ wp, const float* __restrict__ bp,
                   int* __restrict__ count, int* __restrict__ active) {
    __shared__ float red[4];
    float m = 0.f;   // c2 > 0 always
#pragma unroll
    for (int i = 0; i < 4; ++i)
        m = fmaxf(m, c2A[threadIdx.x + i * 256]);
#pragma unroll
    for (int off = 32; off; off >>= 1) m = fmaxf(m, __shfl_xor(m, off));
    if ((threadIdx.x & 63) == 0) red[threadIdx.x >> 6] = m;
    __syncthreads();
    const float c2 = fmaxf(fmaxf(red[0], red[1]), fmaxf(red[2], red[3]));
    const float Cmax = __builtin_sqrtf(c2);

    const int row = blockIdx.x * 256 + threadIdx.x;
    const float bound = __builtin_fmaf(
        __builtin_fabsf(wp[0]) * __builtin_sqrtf(ssqA[row]), Cmax, bp[0]);
    if (dgl[row] - bound < MARGIN) {
        int slot = atomicAdd(count, 1);
        active[slot] = row;
    }
}

// ---------------------------------------------------------------------------
// row: one block per surviving row (grid-stride over slots; ~10 expected).
// Computes all 1024 logits (4 speakers per thread: j = c*256 + tid, the
// SAME (wave,lane)->j mapping the old chunked active_kernel used), then
// reduces with the identical arithmetic tree:
//   per chunk c: wave-butterfly max -> wave-butterfly sumexp -> 4-wave
//   combine (old active_kernel tail) -> 4-chunk combine (old merge_kernel)
// so the result is bit-identical to R11.  atomicAdds row loss into out.
// ---------------------------------------------------------------------------
__global__ __launch_bounds__(256)
void row_kernel(const float* __restrict__ e, const float* __restrict__ sumf,
                const float* __restrict__ dgl,
                const int* __restrict__ count, const int* __restrict__ active,
                const float* __restrict__ wp, const float* __restrict__ bp,
                float* __restrict__ out) {
    __shared__ float er[D_EMB];
    __shared__ float2 red2[4][4];   // [chunk][wave]
    const int tid = threadIdx.x;
    const int wv = tid >> 6;
    const int cnt = *count;
    const float w = wp[0], bb = bp[0];

    for (int slot = blockIdx.x; slot < cnt; slot += gridDim.x) {
        const int row = active[slot];
        __syncthreads();   // protect er/red2 from previous iteration
        er[tid] = e[(size_t)row * D_EMB + tid];
        er[tid + 256] = e[(size_t)row * D_EMB + 256 + tid];
        __syncthreads();

        const float dglr = dgl[row];
        const int dcol = row >> 5;

#pragma unroll
        for (int c = 0; c < 4; ++c) {
            const int j = c * 256 + tid;          // speaker (column) index
            const float* sp = sumf + (size_t)j * D_EMB;
            float d0 = 0.f, d1 = 0.f, d2 = 0.f, d3 = 0.f;
            for (int k = 0; k < D_EMB; k += 4) {
                float4 s4 = *(const float4*)(sp + k);
                d0 = __builtin_fmaf(er[k + 0], s4.x, d0);
                d1 = __builtin_fmaf(er[k + 1], s4.y, d1);
                d2 = __builtin_fmaf(er[k + 2], s4.z, d2);
                d3 = __builtin_fmaf(er[k + 3], s4.w, d3);
            }
            const float dot = (d0 + d1) + (d2 + d3);
            float lg = __builtin_fmaf(w, dot * (1.0f / M_UTT), bb);
            if (j == dcol) lg = dglr;             // exact diag substitution

            float mx = lg;
#pragma unroll
            for (int off = 32; off; off >>= 1)
                mx = fmaxf(mx, __shfl_xor(mx, off));
            float ss = __expf(lg - mx);
#pragma unroll
            for (int off = 32; off; off >>= 1) ss += __shfl_xor(ss, off);
            if ((tid & 63) == 0) {
                float2 v; v.x = mx; v.y = ss; red2[c][wv] = v;
            }
        }
        __syncthreads();

        if (tid == 0) {
            // Old active_kernel tail, per chunk (identical order):
            float2 pm[4];
#pragma unroll
            for (int c = 0; c < 4; ++c) {
                float M = fmaxf(fmaxf(red2[c][0].x, red2[c][1].x),
                                fmaxf(red2[c][2].x, red2[c][3].x));
                float S = red2[c][0].y * __expf(red2[c][0].x - M)
                        + red2[c][1].y * __expf(red2[c][1].x - M)
                        + red2[c][2].y * __expf(red2[c][2].x - M)
                        + red2[c][3].y * __expf(red2[c][3].x - M);
                pm[c].x = M; pm[c].y = S;
            }
            // Old merge_kernel combine (identical order):
            float M = fmaxf(fmaxf(pm[0].x, pm[1].x), fmaxf(pm[2].x, pm[3].x));
            float S = pm[0].y * __expf(pm[0].x - M) + pm[1].y * __expf(pm[1].x - M)
                    + pm[2].y * __expf(pm[2].x - M) + pm[3].y * __expf(pm[3].x - M);
            float loss = M + __logf(S) - dglr;
            atomicAdd(out, loss * (1.0f / NROWS));
        }
    }
}

// ===========================================================================
// FALLBACK PATH (round-1 fp32 vector kernels) — used if ws_size is too small.
// ===========================================================================

__global__ void centroid_kernel(const float* __restrict__ e,
                                float* __restrict__ cent) {
    int gid = blockIdx.x * 256 + threadIdx.x;
    int n = gid >> 9;
    int d = gid & 511;
    const float* p = e + ((size_t)n * M_UTT) * D_EMB + d;
    float s = 0.f;
#pragma unroll
    for (int m = 0; m < M_UTT; ++m) s += p[(size_t)m * D_EMB];
    cent[gid] = s * (1.0f / M_UTT);
}

__global__ void normsq_kernel(const float* __restrict__ e,
                              float* __restrict__ nsq) {
    int wv = threadIdx.x >> 6;
    int lane = threadIdx.x & 63;
    int row = blockIdx.x * 4 + wv;
    const float* p = e + (size_t)row * D_EMB + lane;
    float s = 0.f;
#pragma unroll
    for (int j = 0; j < 8; ++j) { float x = p[j * 64]; s += x * x; }
#pragma unroll
    for (int off = 32; off; off >>= 1) s += __shfl_xor(s, off);
    if (lane == 0) nsq[row] = s;
}

#define BR 64
#define BC 128
#define BK 16
#define TR 4
#define TC 8

__global__ __launch_bounds__(256, 2)
void ge2e_main(const float* __restrict__ e, const float* __restrict__ cent,
               const float* __restrict__ nsq, const float* __restrict__ wp,
               const float* __restrict__ bp, float* __restrict__ partials) {
    __shared__ float As[BK][BR];
    __shared__ float Bs[BK][BC];
    __shared__ float diagLs[BR];
    __shared__ float red[16];

    const int tid = threadIdx.x;
    const int tx = tid & 15;
    const int ty = tid >> 4;
    const int blk = blockIdx.x;
    const int r0 = blk * BR;

    const float w = *wp;
    const float bb = *bp;

    float m_run[TR], s_run[TR];
#pragma unroll
    for (int i = 0; i < TR; ++i) { m_run[i] = NEG_INF; s_run[i] = 0.f; }

    const int a_row = tid >> 2;
    const int a_k   = (tid & 3) * 4;
    const int b_col = tid >> 1;
    const int b_k   = (tid & 1) * 8;

    for (int ct = 0; ct < N_SPK / BC; ++ct) {
        const int c0 = ct * BC;
        float acc[TR][TC];
#pragma unroll
        for (int i = 0; i < TR; ++i)
#pragma unroll
            for (int j = 0; j < TC; ++j) acc[i][j] = 0.f;

        for (int kk = 0; kk < D_EMB; kk += BK) {
            __syncthreads();
            {
                float4 av = *(const float4*)(e + (size_t)(r0 + a_row) * D_EMB + kk + a_k);
                As[a_k + 0][a_row] = av.x;
                As[a_k + 1][a_row] = av.y;
                As[a_k + 2][a_row] = av.z;
                As[a_k + 3][a_row] = av.w;
            }
            {
                const float* bp0 = cent + (size_t)(c0 + b_col) * D_EMB + kk + b_k;
                float4 bv0 = *(const float4*)(bp0);
                float4 bv1 = *(const float4*)(bp0 + 4);
                Bs[b_k + 0][b_col] = bv0.x;
                Bs[b_k + 1][b_col] = bv0.y;
                Bs[b_k + 2][b_col] = bv0.z;
                Bs[b_k + 3][b_col] = bv0.w;
                Bs[b_k + 4][b_col] = bv1.x;
                Bs[b_k + 5][b_col] = bv1.y;
                Bs[b_k + 6][b_col] = bv1.z;
                Bs[b_k + 7][b_col] = bv1.w;
            }
            __syncthreads();

#pragma unroll
            for (int k = 0; k < BK; ++k) {
                float4 a4 = *(const float4*)&As[k][ty * TR];
                float4 b4a = *(const float4*)&Bs[k][tx * TC];
                float4 b4b = *(const float4*)&Bs[k][tx * TC + 4];
                float av[TR] = {a4.x, a4.y, a4.z, a4.w};
                float bv[TC] = {b4a.x, b4a.y, b4a.z, b4a.w,
                                b4b.x, b4b.y, b4b.z, b4b.w};
#pragma unroll
                for (int i = 0; i < TR; ++i)
#pragma unroll
                    for (int j = 0; j < TC; ++j)
                        acc[i][j] = __builtin_fmaf(av[i], bv[j], acc[i][j]);
            }
        }

#pragma unroll
        for (int i = 0; i < TR; ++i) {
            const int grow = r0 + ty * TR + i;
            const int dcol = grow >> 5;
            float lv[TC];
#pragma unroll
            for (int j = 0; j < TC; ++j) {
                const int gcol = c0 + tx * TC + j;
                float v = acc[i][j];
                float lg;
                if (gcol == dcol) {
                    lg = __builtin_fmaf(w, __builtin_fmaf(32.0f, v,
                             (1.0f / 31.0f) * nsq[grow]), bb);
                    diagLs[ty * TR + i] = lg;
                } else {
                    lg = __builtin_fmaf(w, v, bb);
                }
                lv[j] = lg;
            }
            float mx = lv[0];
#pragma unroll
            for (int j = 1; j < TC; ++j) mx = fmaxf(mx, lv[j]);
#pragma unroll
            for (int off = 8; off; off >>= 1) mx = fmaxf(mx, __shfl_xor(mx, off));
            float ss = 0.f;
#pragma unroll
            for (int j = 0; j < TC; ++j) ss += __expf(lv[j] - mx);
#pragma unroll
            for (int off = 8; off; off >>= 1) ss += __shfl_xor(ss, off);
            float nm = fmaxf(m_run[i], mx);
            s_run[i] = s_run[i] * __expf(m_run[i] - nm) + ss * __expf(mx - nm);
            m_run[i] = nm;
        }
    }

    __syncthreads();
    if (tx == 0) {
        float part = 0.f;
#pragma unroll
        for (int i = 0; i < TR; ++i) {
            const int lr = ty * TR + i;
            part += m_run[i] + __logf(s_run[i]) - diagLs[lr];
        }
        red[ty] = part;
    }
    __syncthreads();
    if (tid == 0) {
        float t = 0.f;
#pragma unroll
        for (int i = 0; i < 16; ++i) t += red[i];
        partials[blk] = t;
    }
}

__global__ void reduce_kernel(const float* __restrict__ partials,
                              float* __restrict__ out) {
    __shared__ float red[4];
    int tid = threadIdx.x;
    float v = partials[tid] + partials[tid + 256];
#pragma unroll
    for (int off = 32; off; off >>= 1) v += __shfl_xor(v, off);
    if ((tid & 63) == 0) red[tid >> 6] = v;
    __syncthreads();
    if (tid == 0)
        out[0] = (red[0] + red[1] + red[2] + red[3]) * (1.0f / NROWS);
}

// ===========================================================================

extern "C" void kernel_launch(void* const* d_in, const int* in_sizes, int n_in,
                              void* d_out, int out_size, void* d_ws, size_t ws_size,
                              hipStream_t stream) {
    const float* e  = (const float*)d_in[0];   // [1024,32,512] f32
    const float* wp = (const float*)d_in[1];   // scalar
    const float* bp = (const float*)d_in[2];   // scalar
    float* out = (float*)d_out;

    // Fast-path workspace layout (bytes):
    //   sumf 2097152 | ssqA 131072 | dgl 131072 | active 131072 |
    //   c2A 4096 | count 4
    const size_t NEED_FAST = 2494468ull;

    if (ws_size >= NEED_FAST) {
        char* base = (char*)d_ws;
        float*  sumf   = (float*) (base);
        float*  ssqA   = (float*) (base + 2097152ull);
        float*  dgl    = (float*) (base + 2228224ull);
        int*    active = (int*)   (base + 2359296ull);
        float*  c2A    = (float*) (base + 2490368ull);
        int*    count  = (int*)   (base + 2494464ull);

        prep_kernel<<<N_SPK, 256, 0, stream>>>(e, sumf, ssqA, dgl, c2A,
                                               wp, bp, out, count);
        select_kernel<<<NROWS / 256, 256, 0, stream>>>(ssqA, dgl, c2A,
                                                       wp, bp, count, active);
        row_kernel<<<64, 256, 0, stream>>>(e, sumf, dgl, count, active,
                                           wp, bp, out);
    } else {
        float* ws = (float*)d_ws;
        float* cent     = ws;
        float* nsq      = ws + 524288;
        float* partials = ws + 524288 + 32768;

        centroid_kernel<<<N_SPK * D_EMB / 256, 256, 0, stream>>>(e, cent);
        normsq_kernel<<<NROWS / 4, 256, 0, stream>>>(e, nsq);
        ge2e_main<<<NROWS / BR, 256, 0, stream>>>(e, cent, nsq, wp, bp, partials);
        reduce_kernel<<<1, 256, 0, stream>>>(partials, out);
    }
}

// Round 3
// 162.482 us; speedup vs baseline: 1.0004x; 1.0004x over previous
//
#include <hip/hip_runtime.h>

// Problem constants (fixed by the reference).
#define N_SPK 1024
#define M_UTT 32
#define D_EMB 512
#define NROWS (N_SPK * M_UTT)   // 32768

#define NEG_INF (-__builtin_inff())
#define MARGIN 25.0f   // skip row iff dgl - rowbound >= MARGIN (err < 1.4e-8/row)

using f32x4 = __attribute__((ext_vector_type(4))) float;

// ===========================================================================
// FAST PATH (round 13): prune-then-compute, 3 dispatches.
//
// R12 post-mortem: fusing active+merge with a serial 4-chunk loop per block
// collapsed parallelism to 40 waves -> row_kernel 60.6us at 139 GB/s
// (latency-bound).  R13 keeps the fusion but restores full parallelism:
// ONE BLOCK OF 1024 THREADS per surviving row; thread tid computes speaker
// j=tid with the identical per-speaker dot chain.  Wave w (=tid>>6) holds
// exactly the same 64 j-values in the same lanes as old (chunk c=w>>2,
// wave wv=w&3), so per-wave butterflies are bit-identical; thread 0 replays
// the old per-chunk + merge combine in the old order -> absmax stays 0.0.
//
// Math unchanged from R10: dgl ~ 2641 +- 630 while every off-diag logit is
// bounded by |w|*||e||*max||c|| + b ~ 459 (Cauchy-Schwarz).  Rows with
// dgl - bound >= 25 nats contribute exactly-0 loss in the reference too.
// Survivors (~10 rows) get an exact fp32 1024-logit max-carrying logsumexp.
//
// R11 kept: no init dispatch (prep block 0 zeroes out/count); c2A
// per-speaker array instead of device atomicMax.
// R8 lesson kept: no device-scope __threadfence in wide kernels; all
// cross-kernel deps go through dispatch boundaries (same stream).
// ===========================================================================

// ---------------------------------------------------------------------------
// prep: one block per speaker n (32 rows x 512 dims).  Reads e ONCE.
//  - sumf[n*512+d] = sum_m e[n][m][d]      (fp32 speaker sum, 2 MB)
//  - ssqA[row]     = ||e_row||^2
//  - dgl[row]      = w*(e.sum + ||e||^2/31) + b   (exact fp32 diag logit)
//  - c2A[n]        = ||c_n||^2             (per-speaker, no atomics)
//  - block 0 zeroes out[0] and *count (replaces init dispatch)
// Row data retained in registers across the centroid barrier (R7-verified).
// ---------------------------------------------------------------------------
__global__ __launch_bounds__(256)
void prep_kernel(const float* __restrict__ e,
                 float* __restrict__ sumf, float* __restrict__ ssqA,
                 float* __restrict__ dgl, float* __restrict__ c2A,
                 const float* __restrict__ wp, const float* __restrict__ bp,
                 float* __restrict__ out, int* __restrict__ count) {
    __shared__ float csum[4][D_EMB];   // 8 KiB
    __shared__ float c2red[4];
    const int n = blockIdx.x;
    const int wv = threadIdx.x >> 6, l = threadIdx.x & 63;

    if (n == 0 && threadIdx.x == 0) { out[0] = 0.f; *count = 0; }

    float xs[8][8];     // retained row data (lane's 8 dims x 8 rows)
    float ssq[8];       // per-row ||e||^2 (wave-uniform after butterfly)
    float cacc[8];
#pragma unroll
    for (int j = 0; j < 8; ++j) cacc[j] = 0.f;

#pragma unroll
    for (int mi = 0; mi < 8; ++mi) {
        const int m = mi * 4 + wv;
        const size_t row = (size_t)n * M_UTT + m;
        const float* p = e + row * D_EMB + l * 8;
        float4 x0 = *(const float4*)p;
        float4 x1 = *(const float4*)(p + 4);
        xs[mi][0] = x0.x; xs[mi][1] = x0.y; xs[mi][2] = x0.z; xs[mi][3] = x0.w;
        xs[mi][4] = x1.x; xs[mi][5] = x1.y; xs[mi][6] = x1.z; xs[mi][7] = x1.w;
        float sq = 0.f;
#pragma unroll
        for (int j = 0; j < 8; ++j) {
            float x = xs[mi][j];
            cacc[j] += x;
            sq = __builtin_fmaf(x, x, sq);
        }
#pragma unroll
        for (int off = 32; off; off >>= 1) sq += __shfl_xor(sq, off);
        ssq[mi] = sq;
        if (l == 0) ssqA[row] = sq;
    }

#pragma unroll
    for (int j = 0; j < 8; ++j) csum[wv][l * 8 + j] = cacc[j];
    __syncthreads();
    float c2acc = 0.f;
    for (int d = threadIdx.x; d < D_EMB; d += 256) {
        float s = csum[0][d] + csum[1][d] + csum[2][d] + csum[3][d];
        csum[0][d] = s;                               // full speaker sum
        sumf[(size_t)n * D_EMB + d] = s;
        float c = s * (1.0f / M_UTT);
        c2acc = __builtin_fmaf(c, c, c2acc);
    }
#pragma unroll
    for (int off = 32; off; off >>= 1) c2acc += __shfl_xor(c2acc, off);
    if (l == 0) c2red[wv] = c2acc;
    __syncthreads();   // csum[0] full sums + c2red visible
    if (threadIdx.x == 0)
        c2A[n] = (c2red[0] + c2red[1]) + (c2red[2] + c2red[3]);

    // Exact fp32 diag: dgl[row] = w*(e.sum + ssq/31) + b.
    float sv[8];
#pragma unroll
    for (int j = 0; j < 8; ++j) sv[j] = csum[0][l * 8 + j];
    const float w = wp[0], bb = bp[0];
#pragma unroll
    for (int mi = 0; mi < 8; ++mi) {
        float dg = 0.f;
#pragma unroll
        for (int j = 0; j < 8; ++j) dg = __builtin_fmaf(xs[mi][j], sv[j], dg);
#pragma unroll
        for (int off = 32; off; off >>= 1) dg += __shfl_xor(dg, off);
        if (l == 0) {
            const size_t row = (size_t)n * M_UTT + mi * 4 + wv;
            dgl[row] = __builtin_fmaf(w, dg + ssq[mi] * (1.0f / 31.0f), bb);
        }
    }
}

// ---------------------------------------------------------------------------
// select: one thread per row.  Each block first max-reduces c2A (4 KB,
// L2-hot) to Cmax^2 — exact same max the old atomicMax produced (fmaxf is
// rounding-free, order-independent).  Row survives iff
// dgl - (|w|*||e||*Cmax + b) < MARGIN.  Survivors appended to active[]
// (device atomic; ~10 appends total).
// ---------------------------------------------------------------------------
__global__ __launch_bounds__(256)
void select_kernel(const float* __restrict__ ssqA, const float* __restrict__ dgl,
                   const float* __restrict__ c2A,
                   const float* __restrict__ wp, const float* __restrict__ bp,
                   int* __restrict__ count, int* __restrict__ active) {
    __shared__ float red[4];
    float m = 0.f;   // c2 > 0 always
#pragma unroll
    for (int i = 0; i < 4; ++i)
        m = fmaxf(m, c2A[threadIdx.x + i * 256]);
#pragma unroll
    for (int off = 32; off; off >>= 1) m = fmaxf(m, __shfl_xor(m, off));
    if ((threadIdx.x & 63) == 0) red[threadIdx.x >> 6] = m;
    __syncthreads();
    const float c2 = fmaxf(fmaxf(red[0], red[1]), fmaxf(red[2], red[3]));
    const float Cmax = __builtin_sqrtf(c2);

    const int row = blockIdx.x * 256 + threadIdx.x;
    const float bound = __builtin_fmaf(
        __builtin_fabsf(wp[0]) * __builtin_sqrtf(ssqA[row]), Cmax, bp[0]);
    if (dgl[row] - bound < MARGIN) {
        int slot = atomicAdd(count, 1);
        active[slot] = row;
    }
}

// ---------------------------------------------------------------------------
// row: ONE 1024-THREAD BLOCK per surviving row (grid-stride over slots; ~10
// expected).  Thread tid computes speaker j=tid with the identical dot
// chain the old chunked active_kernel used.  Wave w=tid>>6 holds exactly
// the old (chunk w>>2, wave w&3) lane set, so the per-wave butterflies are
// bit-identical; red2[4c+wv] == old red2[c][wv].  Thread 0 replays the old
// per-chunk combine + merge combine in the identical order, then atomicAdds
// the row loss.  Bit-exact vs R11; 4x the parallelism of the failed R12.
// ---------------------------------------------------------------------------
__global__ __launch_bounds__(1024)
void row_kernel(const float* __restrict__ e, const float* __restrict__ sumf,
                const float* __restrict__ dgl,
                const int* __restrict__ count, const int* __restrict__ active,
                const float* __restrict__ wp, const float* __restrict__ bp,
                float* __restrict__ out) {
    __shared__ float er[D_EMB];
    __shared__ float2 red2[16];    // [wave] = old [chunk=w>>2][wv=w&3]
    const int tid = threadIdx.x;
    const int wave = tid >> 6;
    const int cnt = *count;
    const float w = wp[0], bb = bp[0];

    for (int slot = blockIdx.x; slot < cnt; slot += gridDim.x) {
        const int row = active[slot];
        __syncthreads();   // protect er/red2 from previous iteration
        if (tid < D_EMB) er[tid] = e[(size_t)row * D_EMB + tid];
        __syncthreads();

        const float dglr = dgl[row];
        const int dcol = row >> 5;

        const int j = tid;                        // speaker (column) index
        const float* sp = sumf + (size_t)j * D_EMB;
        float d0 = 0.f, d1 = 0.f, d2 = 0.f, d3 = 0.f;
        for (int k = 0; k < D_EMB; k += 4) {
            float4 s4 = *(const float4*)(sp + k);
            d0 = __builtin_fmaf(er[k + 0], s4.x, d0);
            d1 = __builtin_fmaf(er[k + 1], s4.y, d1);
            d2 = __builtin_fmaf(er[k + 2], s4.z, d2);
            d3 = __builtin_fmaf(er[k + 3], s4.w, d3);
        }
        const float dot = (d0 + d1) + (d2 + d3);
        float lg = __builtin_fmaf(w, dot * (1.0f / M_UTT), bb);
        if (j == dcol) lg = dglr;                 // exact diag substitution

        float mx = lg;
#pragma unroll
        for (int off = 32; off; off >>= 1) mx = fmaxf(mx, __shfl_xor(mx, off));
        float ss = __expf(lg - mx);
#pragma unroll
        for (int off = 32; off; off >>= 1) ss += __shfl_xor(ss, off);
        if ((tid & 63) == 0) { float2 v; v.x = mx; v.y = ss; red2[wave] = v; }
        __syncthreads();

        if (tid == 0) {
            // Old active_kernel tail, per chunk c (identical order):
            float2 pm[4];
#pragma unroll
            for (int c = 0; c < 4; ++c) {
                float M = fmaxf(fmaxf(red2[4 * c + 0].x, red2[4 * c + 1].x),
                                fmaxf(red2[4 * c + 2].x, red2[4 * c + 3].x));
                float S = red2[4 * c + 0].y * __expf(red2[4 * c + 0].x - M)
                        + red2[4 * c + 1].y * __expf(red2[4 * c + 1].x - M)
                        + red2[4 * c + 2].y * __expf(red2[4 * c + 2].x - M)
                        + red2[4 * c + 3].y * __expf(red2[4 * c + 3].x - M);
                pm[c].x = M; pm[c].y = S;
            }
            // Old merge_kernel combine (identical order):
            float M = fmaxf(fmaxf(pm[0].x, pm[1].x), fmaxf(pm[2].x, pm[3].x));
            float S = pm[0].y * __expf(pm[0].x - M) + pm[1].y * __expf(pm[1].x - M)
                    + pm[2].y * __expf(pm[2].x - M) + pm[3].y * __expf(pm[3].x - M);
            float loss = M + __logf(S) - dglr;
            atomicAdd(out, loss * (1.0f / NROWS));
        }
    }
}

// ===========================================================================
// FALLBACK PATH (round-1 fp32 vector kernels) — used if ws_size is too small.
// ===========================================================================

__global__ void centroid_kernel(const float* __restrict__ e,
                                float* __restrict__ cent) {
    int gid = blockIdx.x * 256 + threadIdx.x;
    int n = gid >> 9;
    int d = gid & 511;
    const float* p = e + ((size_t)n * M_UTT) * D_EMB + d;
    float s = 0.f;
#pragma unroll
    for (int m = 0; m < M_UTT; ++m) s += p[(size_t)m * D_EMB];
    cent[gid] = s * (1.0f / M_UTT);
}

__global__ void normsq_kernel(const float* __restrict__ e,
                              float* __restrict__ nsq) {
    int wv = threadIdx.x >> 6;
    int lane = threadIdx.x & 63;
    int row = blockIdx.x * 4 + wv;
    const float* p = e + (size_t)row * D_EMB + lane;
    float s = 0.f;
#pragma unroll
    for (int j = 0; j < 8; ++j) { float x = p[j * 64]; s += x * x; }
#pragma unroll
    for (int off = 32; off; off >>= 1) s += __shfl_xor(s, off);
    if (lane == 0) nsq[row] = s;
}

#define BR 64
#define BC 128
#define BK 16
#define TR 4
#define TC 8

__global__ __launch_bounds__(256, 2)
void ge2e_main(const float* __restrict__ e, const float* __restrict__ cent,
               const float* __restrict__ nsq, const float* __restrict__ wp,
               const float* __restrict__ bp, float* __restrict__ partials) {
    __shared__ float As[BK][BR];
    __shared__ float Bs[BK][BC];
    __shared__ float diagLs[BR];
    __shared__ float red[16];

    const int tid = threadIdx.x;
    const int tx = tid & 15;
    const int ty = tid >> 4;
    const int blk = blockIdx.x;
    const int r0 = blk * BR;

    const float w = *wp;
    const float bb = *bp;

    float m_run[TR], s_run[TR];
#pragma unroll
    for (int i = 0; i < TR; ++i) { m_run[i] = NEG_INF; s_run[i] = 0.f; }

    const int a_row = tid >> 2;
    const int a_k   = (tid & 3) * 4;
    const int b_col = tid >> 1;
    const int b_k   = (tid & 1) * 8;

    for (int ct = 0; ct < N_SPK / BC; ++ct) {
        const int c0 = ct * BC;
        float acc[TR][TC];
#pragma unroll
        for (int i = 0; i < TR; ++i)
#pragma unroll
            for (int j = 0; j < TC; ++j) acc[i][j] = 0.f;

        for (int kk = 0; kk < D_EMB; kk += BK) {
            __syncthreads();
            {
                float4 av = *(const float4*)(e + (size_t)(r0 + a_row) * D_EMB + kk + a_k);
                As[a_k + 0][a_row] = av.x;
                As[a_k + 1][a_row] = av.y;
                As[a_k + 2][a_row] = av.z;
                As[a_k + 3][a_row] = av.w;
            }
            {
                const float* bp0 = cent + (size_t)(c0 + b_col) * D_EMB + kk + b_k;
                float4 bv0 = *(const float4*)(bp0);
                float4 bv1 = *(const float4*)(bp0 + 4);
                Bs[b_k + 0][b_col] = bv0.x;
                Bs[b_k + 1][b_col] = bv0.y;
                Bs[b_k + 2][b_col] = bv0.z;
                Bs[b_k + 3][b_col] = bv0.w;
                Bs[b_k + 4][b_col] = bv1.x;
                Bs[b_k + 5][b_col] = bv1.y;
                Bs[b_k + 6][b_col] = bv1.z;
                Bs[b_k + 7][b_col] = bv1.w;
            }
            __syncthreads();

#pragma unroll
            for (int k = 0; k < BK; ++k) {
                float4 a4 = *(const float4*)&As[k][ty * TR];
                float4 b4a = *(const float4*)&Bs[k][tx * TC];
                float4 b4b = *(const float4*)&Bs[k][tx * TC + 4];
                float av[TR] = {a4.x, a4.y, a4.z, a4.w};
                float bv[TC] = {b4a.x, b4a.y, b4a.z, b4a.w,
                                b4b.x, b4b.y, b4b.z, b4b.w};
#pragma unroll
                for (int i = 0; i < TR; ++i)
#pragma unroll
                    for (int j = 0; j < TC; ++j)
                        acc[i][j] = __builtin_fmaf(av[i], bv[j], acc[i][j]);
            }
        }

#pragma unroll
        for (int i = 0; i < TR; ++i) {
            const int grow = r0 + ty * TR + i;
            const int dcol = grow >> 5;
            float lv[TC];
#pragma unroll
            for (int j = 0; j < TC; ++j) {
                const int gcol = c0 + tx * TC + j;
                float v = acc[i][j];
                float lg;
                if (gcol == dcol) {
                    lg = __builtin_fmaf(w, __builtin_fmaf(32.0f, v,
                             (1.0f / 31.0f) * nsq[grow]), bb);
                    diagLs[ty * TR + i] = lg;
                } else {
                    lg = __builtin_fmaf(w, v, bb);
                }
                lv[j] = lg;
            }
            float mx = lv[0];
#pragma unroll
            for (int j = 1; j < TC; ++j) mx = fmaxf(mx, lv[j]);
#pragma unroll
            for (int off = 8; off; off >>= 1) mx = fmaxf(mx, __shfl_xor(mx, off));
            float ss = 0.f;
#pragma unroll
            for (int j = 0; j < TC; ++j) ss += __expf(lv[j] - mx);
#pragma unroll
            for (int off = 8; off; off >>= 1) ss += __shfl_xor(ss, off);
            float nm = fmaxf(m_run[i], mx);
            s_run[i] = s_run[i] * __expf(m_run[i] - nm) + ss * __expf(mx - nm);
            m_run[i] = nm;
        }
    }

    __syncthreads();
    if (tx == 0) {
        float part = 0.f;
#pragma unroll
        for (int i = 0; i < TR; ++i) {
            const int lr = ty * TR + i;
            part += m_run[i] + __logf(s_run[i]) - diagLs[lr];
        }
        red[ty] = part;
    }
    __syncthreads();
    if (tid == 0) {
        float t = 0.f;
#pragma unroll
        for (int i = 0; i < 16; ++i) t += red[i];
        partials[blk] = t;
    }
}

__global__ void reduce_kernel(const float* __restrict__ partials,
                              float* __restrict__ out) {
    __shared__ float red[4];
    int tid = threadIdx.x;
    float v = partials[tid] + partials[tid + 256];
#pragma unroll
    for (int off = 32; off; off >>= 1) v += __shfl_xor(v, off);
    if ((tid & 63) == 0) red[tid >> 6] = v;
    __syncthreads();
    if (tid == 0)
        out[0] = (red[0] + red[1] + red[2] + red[3]) * (1.0f / NROWS);
}

// ===========================================================================

extern "C" void kernel_launch(void* const* d_in, const int* in_sizes, int n_in,
                              void* d_out, int out_size, void* d_ws, size_t ws_size,
                              hipStream_t stream) {
    const float* e  = (const float*)d_in[0];   // [1024,32,512] f32
    const float* wp = (const float*)d_in[1];   // scalar
    const float* bp = (const float*)d_in[2];   // scalar
    float* out = (float*)d_out;

    // Fast-path workspace layout (bytes):
    //   sumf 2097152 | ssqA 131072 | dgl 131072 | active 131072 |
    //   c2A 4096 | count 4
    const size_t NEED_FAST = 2494468ull;

    if (ws_size >= NEED_FAST) {
        char* base = (char*)d_ws;
        float*  sumf   = (float*) (base);
        float*  ssqA   = (float*) (base + 2097152ull);
        float*  dgl    = (float*) (base + 2228224ull);
        int*    active = (int*)   (base + 2359296ull);
        float*  c2A    = (float*) (base + 2490368ull);
        int*    count  = (int*)   (base + 2494464ull);

        prep_kernel<<<N_SPK, 256, 0, stream>>>(e, sumf, ssqA, dgl, c2A,
                                               wp, bp, out, count);
        select_kernel<<<NROWS / 256, 256, 0, stream>>>(ssqA, dgl, c2A,
                                                       wp, bp, count, active);
        row_kernel<<<64, 1024, 0, stream>>>(e, sumf, dgl, count, active,
                                            wp, bp, out);
    } else {
        float* ws = (float*)d_ws;
        float* cent     = ws;
        float* nsq      = ws + 524288;
        float* partials = ws + 524288 + 32768;

        centroid_kernel<<<N_SPK * D_EMB / 256, 256, 0, stream>>>(e, cent);
        normsq_kernel<<<NROWS / 4, 256, 0, stream>>>(e, nsq);
        ge2e_main<<<NROWS / BR, 256, 0, stream>>>(e, cent, nsq, wp, bp, partials);
        reduce_kernel<<<1, 256, 0, stream>>>(partials, out);
    }
}

// Round 4
// 123.483 us; speedup vs baseline: 1.3163x; 1.3158x over previous
//
#include <hip/hip_runtime.h>

// Problem constants (fixed by the reference).
#define N_SPK 1024
#define M_UTT 32
#define D_EMB 512
#define NROWS (N_SPK * M_UTT)   // 32768

#define NEG_INF (-__builtin_inff())
#define MARGIN 25.0f   // skip row iff dgl - rowbound >= MARGIN (err < 1.4e-8/row)

using f32x4 = __attribute__((ext_vector_type(4))) float;

// ===========================================================================
// FAST PATH (round 14): prune-then-compute, 3 dispatches.
//
// R12/R13 post-mortem: the active phase is bound by memory-level parallelism
// ACROSS blocks (10 blocks -> 139 GB/s, 60us, independent of threads/block).
// R14 restores R11's (slot, chunk-of-256-speakers) item decomposition
// (~64 concurrent 256-thread blocks) and fuses the merge via a device-scope
// done-counter: each item block release-stores its float2 partial, adds its
// item count to doneCnt; the unique block crossing cnt*4 acquires and
// replays the OLD merge combine for every slot in the identical arithmetic
// order -> bit-exact (absmax 0.0).
//
// XCD-affinity (perf-only): chunk = (blockIdx%8)>>1 so each XCD's L2
// streams only one 512KB chunk of sumf (blockIdx->XCD is %8 round-robin
// on MI355X; if not, this is merely neutral).
//
// Math unchanged from R10: dgl ~ 2641 +- 630 while every off-diag logit is
// bounded by |w|*||e||*max||c|| + b ~ 459 (Cauchy-Schwarz).  Rows with
// dgl - bound >= 25 nats contribute exactly-0 loss in the reference too.
// Survivors (~10-20 rows) get an exact fp32 1024-logit logsumexp.
//
// R11 kept: no init dispatch (prep block 0 zeroes out/count/doneCnt); c2A
// per-speaker array instead of device atomicMax.
// ===========================================================================

// ---------------------------------------------------------------------------
// prep: one block per speaker n (32 rows x 512 dims).  Reads e ONCE.
//  - sumf[n*512+d] = sum_m e[n][m][d]      (fp32 speaker sum, 2 MB)
//  - ssqA[row]     = ||e_row||^2
//  - dgl[row]      = w*(e.sum + ||e||^2/31) + b   (exact fp32 diag logit)
//  - c2A[n]        = ||c_n||^2             (per-speaker, no atomics)
//  - block 0 zeroes out[0], *count, *doneCnt (replaces init dispatch)
// ---------------------------------------------------------------------------
__global__ __launch_bounds__(256)
void prep_kernel(const float* __restrict__ e,
                 float* __restrict__ sumf, float* __restrict__ ssqA,
                 float* __restrict__ dgl, float* __restrict__ c2A,
                 const float* __restrict__ wp, const float* __restrict__ bp,
                 float* __restrict__ out, int* __restrict__ count,
                 int* __restrict__ doneCnt) {
    __shared__ float csum[4][D_EMB];   // 8 KiB
    __shared__ float c2red[4];
    const int n = blockIdx.x;
    const int wv = threadIdx.x >> 6, l = threadIdx.x & 63;

    if (n == 0 && threadIdx.x == 0) { out[0] = 0.f; *count = 0; *doneCnt = 0; }

    float xs[8][8];     // retained row data (lane's 8 dims x 8 rows)
    float ssq[8];       // per-row ||e||^2 (wave-uniform after butterfly)
    float cacc[8];
#pragma unroll
    for (int j = 0; j < 8; ++j) cacc[j] = 0.f;

#pragma unroll
    for (int mi = 0; mi < 8; ++mi) {
        const int m = mi * 4 + wv;
        const size_t row = (size_t)n * M_UTT + m;
        const float* p = e + row * D_EMB + l * 8;
        float4 x0 = *(const float4*)p;
        float4 x1 = *(const float4*)(p + 4);
        xs[mi][0] = x0.x; xs[mi][1] = x0.y; xs[mi][2] = x0.z; xs[mi][3] = x0.w;
        xs[mi][4] = x1.x; xs[mi][5] = x1.y; xs[mi][6] = x1.z; xs[mi][7] = x1.w;
        float sq = 0.f;
#pragma unroll
        for (int j = 0; j < 8; ++j) {
            float x = xs[mi][j];
            cacc[j] += x;
            sq = __builtin_fmaf(x, x, sq);
        }
#pragma unroll
        for (int off = 32; off; off >>= 1) sq += __shfl_xor(sq, off);
        ssq[mi] = sq;
        if (l == 0) ssqA[row] = sq;
    }

#pragma unroll
    for (int j = 0; j < 8; ++j) csum[wv][l * 8 + j] = cacc[j];
    __syncthreads();
    float c2acc = 0.f;
    for (int d = threadIdx.x; d < D_EMB; d += 256) {
        float s = csum[0][d] + csum[1][d] + csum[2][d] + csum[3][d];
        csum[0][d] = s;                               // full speaker sum
        sumf[(size_t)n * D_EMB + d] = s;
        float c = s * (1.0f / M_UTT);
        c2acc = __builtin_fmaf(c, c, c2acc);
    }
#pragma unroll
    for (int off = 32; off; off >>= 1) c2acc += __shfl_xor(c2acc, off);
    if (l == 0) c2red[wv] = c2acc;
    __syncthreads();   // csum[0] full sums + c2red visible
    if (threadIdx.x == 0)
        c2A[n] = (c2red[0] + c2red[1]) + (c2red[2] + c2red[3]);

    // Exact fp32 diag: dgl[row] = w*(e.sum + ssq/31) + b.
    float sv[8];
#pragma unroll
    for (int j = 0; j < 8; ++j) sv[j] = csum[0][l * 8 + j];
    const float w = wp[0], bb = bp[0];
#pragma unroll
    for (int mi = 0; mi < 8; ++mi) {
        float dg = 0.f;
#pragma unroll
        for (int j = 0; j < 8; ++j) dg = __builtin_fmaf(xs[mi][j], sv[j], dg);
#pragma unroll
        for (int off = 32; off; off >>= 1) dg += __shfl_xor(dg, off);
        if (l == 0) {
            const size_t row = (size_t)n * M_UTT + mi * 4 + wv;
            dgl[row] = __builtin_fmaf(w, dg + ssq[mi] * (1.0f / 31.0f), bb);
        }
    }
}

// ---------------------------------------------------------------------------
// select: one thread per row.  Each block first max-reduces c2A (4 KB,
// L2-hot) to Cmax^2 — exact same max the old atomicMax produced (fmaxf is
// rounding-free, order-independent).  Row survives iff
// dgl - (|w|*||e||*Cmax + b) < MARGIN.  Survivors appended to active[]
// (device atomic; ~10-20 appends total).
// ---------------------------------------------------------------------------
__global__ __launch_bounds__(256)
void select_kernel(const float* __restrict__ ssqA, const float* __restrict__ dgl,
                   const float* __restrict__ c2A,
                   const float* __restrict__ wp, const float* __restrict__ bp,
                   int* __restrict__ count, int* __restrict__ active) {
    __shared__ float red[4];
    float m = 0.f;   // c2 > 0 always
#pragma unroll
    for (int i = 0; i < 4; ++i)
        m = fmaxf(m, c2A[threadIdx.x + i * 256]);
#pragma unroll
    for (int off = 32; off; off >>= 1) m = fmaxf(m, __shfl_xor(m, off));
    if ((threadIdx.x & 63) == 0) red[threadIdx.x >> 6] = m;
    __syncthreads();
    const float c2 = fmaxf(fmaxf(red[0], red[1]), fmaxf(red[2], red[3]));
    const float Cmax = __builtin_sqrtf(c2);

    const int row = blockIdx.x * 256 + threadIdx.x;
    const float bound = __builtin_fmaf(
        __builtin_fabsf(wp[0]) * __builtin_sqrtf(ssqA[row]), Cmax, bp[0]);
    if (dgl[row] - bound < MARGIN) {
        int slot = atomicAdd(count, 1);
        active[slot] = row;
    }
}

// ---------------------------------------------------------------------------
// active (fused merge): item = (slot, chunk of 256 speakers).  Block's chunk
// is fixed by XCD affinity: chunk = (blockIdx%8)>>1; slots are strided over
// the 2-of-8 block subset serving that chunk (g = (bi>>3)*2 + (bi&1),
// stride = gridDim/4).  Each item computes the R11 per-chunk (max,sumexp)
// partial with the identical wave butterflies, release-stores it into pmA
// (64-bit agent-scope atomic), and counts it.  After the loop each block
// adds its item count to doneCnt; the unique block whose add reaches cnt*4
// merges ALL slots with the identical old combine order, atomicAdds each
// row loss into out.  Bit-exact vs R11.
// ---------------------------------------------------------------------------
__global__ __launch_bounds__(256)
void active_kernel(const float* __restrict__ e, const float* __restrict__ sumf,
                   const float* __restrict__ dgl,
                   const int* __restrict__ count, const int* __restrict__ active,
                   const float* __restrict__ wp, const float* __restrict__ bp,
                   float2* __restrict__ pmA, int* __restrict__ doneCnt,
                   float* __restrict__ out) {
    __shared__ float er[D_EMB];
    __shared__ float2 red2[4];
    __shared__ int lastFlag;
    const int tid = threadIdx.x;
    const int cnt = *count;
    if (cnt == 0) return;
    const float w = wp[0], bb = bp[0];

    const int xcd = blockIdx.x & 7;
    const int chunk = xcd >> 1;                       // 2 XCDs per chunk
    const int g = (blockIdx.x >> 3) * 2 + (xcd & 1);  // index within chunk group
    const int gstride = (gridDim.x >> 3) * 2;

    if (tid == 0) lastFlag = 0;
    int myItems = 0;

    for (int slot = g; slot < cnt; slot += gstride) {
        const int row = active[slot];
        __syncthreads();   // protect er/red2 (and lastFlag init, 1st iter)
        er[tid] = e[(size_t)row * D_EMB + tid];
        er[tid + 256] = e[(size_t)row * D_EMB + 256 + tid];
        __syncthreads();

        const int j = chunk * 256 + tid;          // speaker (column) index
        const float* sp = sumf + (size_t)j * D_EMB;
        float d0 = 0.f, d1 = 0.f, d2 = 0.f, d3 = 0.f;
        for (int k = 0; k < D_EMB; k += 4) {
            float4 s4 = *(const float4*)(sp + k);
            d0 = __builtin_fmaf(er[k + 0], s4.x, d0);
            d1 = __builtin_fmaf(er[k + 1], s4.y, d1);
            d2 = __builtin_fmaf(er[k + 2], s4.z, d2);
            d3 = __builtin_fmaf(er[k + 3], s4.w, d3);
        }
        const float dot = (d0 + d1) + (d2 + d3);
        float lg = __builtin_fmaf(w, dot * (1.0f / M_UTT), bb);
        if (j == (row >> 5)) lg = dgl[row];       // exact diag substitution

        float mx = lg;
#pragma unroll
        for (int off = 32; off; off >>= 1) mx = fmaxf(mx, __shfl_xor(mx, off));
        float ss = __expf(lg - mx);
#pragma unroll
        for (int off = 32; off; off >>= 1) ss += __shfl_xor(ss, off);
        if ((tid & 63) == 0) { float2 v; v.x = mx; v.y = ss; red2[tid >> 6] = v; }
        __syncthreads();
        if (tid == 0) {
            // Old active_kernel 4-wave combine (identical order):
            float M = fmaxf(fmaxf(red2[0].x, red2[1].x),
                            fmaxf(red2[2].x, red2[3].x));
            float S = red2[0].y * __expf(red2[0].x - M)
                    + red2[1].y * __expf(red2[1].x - M)
                    + red2[2].y * __expf(red2[2].x - M)
                    + red2[3].y * __expf(red2[3].x - M);
            float2 v; v.x = M; v.y = S;
            __hip_atomic_store((unsigned long long*)&pmA[slot * 4 + chunk],
                               __builtin_bit_cast(unsigned long long, v),
                               __ATOMIC_RELAXED, __HIP_MEMORY_SCOPE_AGENT);
        }
        ++myItems;
    }

    __syncthreads();   // all waves done with their last item's red2/pmA path
    if (tid == 0 && myItems > 0) {
        int old = __hip_atomic_fetch_add(doneCnt, myItems,
                                         __ATOMIC_ACQ_REL,
                                         __HIP_MEMORY_SCOPE_AGENT);
        if (old + myItems == cnt * 4) lastFlag = 1;   // unique crossing block
    }
    __syncthreads();

    if (lastFlag) {
        // Merge ALL slots (old merge_kernel, identical arithmetic order).
        for (int slot = tid; slot < cnt; slot += 256) {
            float2 pm[4];
#pragma unroll
            for (int c = 0; c < 4; ++c) {
                unsigned long long bits = __hip_atomic_load(
                    (unsigned long long*)&pmA[slot * 4 + c],
                    __ATOMIC_RELAXED, __HIP_MEMORY_SCOPE_AGENT);
                pm[c] = __builtin_bit_cast(float2, bits);
            }
            float M = fmaxf(fmaxf(pm[0].x, pm[1].x), fmaxf(pm[2].x, pm[3].x));
            float S = pm[0].y * __expf(pm[0].x - M) + pm[1].y * __expf(pm[1].x - M)
                    + pm[2].y * __expf(pm[2].x - M) + pm[3].y * __expf(pm[3].x - M);
            float loss = M + __logf(S) - dgl[active[slot]];
            atomicAdd(out, loss * (1.0f / NROWS));
        }
    }
}

// ===========================================================================
// FALLBACK PATH (round-1 fp32 vector kernels) — used if ws_size is too small.
// ===========================================================================

__global__ void centroid_kernel(const float* __restrict__ e,
                                float* __restrict__ cent) {
    int gid = blockIdx.x * 256 + threadIdx.x;
    int n = gid >> 9;
    int d = gid & 511;
    const float* p = e + ((size_t)n * M_UTT) * D_EMB + d;
    float s = 0.f;
#pragma unroll
    for (int m = 0; m < M_UTT; ++m) s += p[(size_t)m * D_EMB];
    cent[gid] = s * (1.0f / M_UTT);
}

__global__ void normsq_kernel(const float* __restrict__ e,
                              float* __restrict__ nsq) {
    int wv = threadIdx.x >> 6;
    int lane = threadIdx.x & 63;
    int row = blockIdx.x * 4 + wv;
    const float* p = e + (size_t)row * D_EMB + lane;
    float s = 0.f;
#pragma unroll
    for (int j = 0; j < 8; ++j) { float x = p[j * 64]; s += x * x; }
#pragma unroll
    for (int off = 32; off; off >>= 1) s += __shfl_xor(s, off);
    if (lane == 0) nsq[row] = s;
}

#define BR 64
#define BC 128
#define BK 16
#define TR 4
#define TC 8

__global__ __launch_bounds__(256, 2)
void ge2e_main(const float* __restrict__ e, const float* __restrict__ cent,
               const float* __restrict__ nsq, const float* __restrict__ wp,
               const float* __restrict__ bp, float* __restrict__ partials) {
    __shared__ float As[BK][BR];
    __shared__ float Bs[BK][BC];
    __shared__ float diagLs[BR];
    __shared__ float red[16];

    const int tid = threadIdx.x;
    const int tx = tid & 15;
    const int ty = tid >> 4;
    const int blk = blockIdx.x;
    const int r0 = blk * BR;

    const float w = *wp;
    const float bb = *bp;

    float m_run[TR], s_run[TR];
#pragma unroll
    for (int i = 0; i < TR; ++i) { m_run[i] = NEG_INF; s_run[i] = 0.f; }

    const int a_row = tid >> 2;
    const int a_k   = (tid & 3) * 4;
    const int b_col = tid >> 1;
    const int b_k   = (tid & 1) * 8;

    for (int ct = 0; ct < N_SPK / BC; ++ct) {
        const int c0 = ct * BC;
        float acc[TR][TC];
#pragma unroll
        for (int i = 0; i < TR; ++i)
#pragma unroll
            for (int j = 0; j < TC; ++j) acc[i][j] = 0.f;

        for (int kk = 0; kk < D_EMB; kk += BK) {
            __syncthreads();
            {
                float4 av = *(const float4*)(e + (size_t)(r0 + a_row) * D_EMB + kk + a_k);
                As[a_k + 0][a_row] = av.x;
                As[a_k + 1][a_row] = av.y;
                As[a_k + 2][a_row] = av.z;
                As[a_k + 3][a_row] = av.w;
            }
            {
                const float* bp0 = cent + (size_t)(c0 + b_col) * D_EMB + kk + b_k;
                float4 bv0 = *(const float4*)(bp0);
                float4 bv1 = *(const float4*)(bp0 + 4);
                Bs[b_k + 0][b_col] = bv0.x;
                Bs[b_k + 1][b_col] = bv0.y;
                Bs[b_k + 2][b_col] = bv0.z;
                Bs[b_k + 3][b_col] = bv0.w;
                Bs[b_k + 4][b_col] = bv1.x;
                Bs[b_k + 5][b_col] = bv1.y;
                Bs[b_k + 6][b_col] = bv1.z;
                Bs[b_k + 7][b_col] = bv1.w;
            }
            __syncthreads();

#pragma unroll
            for (int k = 0; k < BK; ++k) {
                float4 a4 = *(const float4*)&As[k][ty * TR];
                float4 b4a = *(const float4*)&Bs[k][tx * TC];
                float4 b4b = *(const float4*)&Bs[k][tx * TC + 4];
                float av[TR] = {a4.x, a4.y, a4.z, a4.w};
                float bv[TC] = {b4a.x, b4a.y, b4a.z, b4a.w,
                                b4b.x, b4b.y, b4b.z, b4b.w};
#pragma unroll
                for (int i = 0; i < TR; ++i)
#pragma unroll
                    for (int j = 0; j < TC; ++j)
                        acc[i][j] = __builtin_fmaf(av[i], bv[j], acc[i][j]);
            }
        }

#pragma unroll
        for (int i = 0; i < TR; ++i) {
            const int grow = r0 + ty * TR + i;
            const int dcol = grow >> 5;
            float lv[TC];
#pragma unroll
            for (int j = 0; j < TC; ++j) {
                const int gcol = c0 + tx * TC + j;
                float v = acc[i][j];
                float lg;
                if (gcol == dcol) {
                    lg = __builtin_fmaf(w, __builtin_fmaf(32.0f, v,
                             (1.0f / 31.0f) * nsq[grow]), bb);
                    diagLs[ty * TR + i] = lg;
                } else {
                    lg = __builtin_fmaf(w, v, bb);
                }
                lv[j] = lg;
            }
            float mx = lv[0];
#pragma unroll
            for (int j = 1; j < TC; ++j) mx = fmaxf(mx, lv[j]);
#pragma unroll
            for (int off = 8; off; off >>= 1) mx = fmaxf(mx, __shfl_xor(mx, off));
            float ss = 0.f;
#pragma unroll
            for (int j = 0; j < TC; ++j) ss += __expf(lv[j] - mx);
#pragma unroll
            for (int off = 8; off; off >>= 1) ss += __shfl_xor(ss, off);
            float nm = fmaxf(m_run[i], mx);
            s_run[i] = s_run[i] * __expf(m_run[i] - nm) + ss * __expf(mx - nm);
            m_run[i] = nm;
        }
    }

    __syncthreads();
    if (tx == 0) {
        float part = 0.f;
#pragma unroll
        for (int i = 0; i < TR; ++i) {
            const int lr = ty * TR + i;
            part += m_run[i] + __logf(s_run[i]) - diagLs[lr];
        }
        red[ty] = part;
    }
    __syncthreads();
    if (tid == 0) {
        float t = 0.f;
#pragma unroll
        for (int i = 0; i < 16; ++i) t += red[i];
        partials[blk] = t;
    }
}

__global__ void reduce_kernel(const float* __restrict__ partials,
                              float* __restrict__ out) {
    __shared__ float red[4];
    int tid = threadIdx.x;
    float v = partials[tid] + partials[tid + 256];
#pragma unroll
    for (int off = 32; off; off >>= 1) v += __shfl_xor(v, off);
    if ((tid & 63) == 0) red[tid >> 6] = v;
    __syncthreads();
    if (tid == 0)
        out[0] = (red[0] + red[1] + red[2] + red[3]) * (1.0f / NROWS);
}

// ===========================================================================

extern "C" void kernel_launch(void* const* d_in, const int* in_sizes, int n_in,
                              void* d_out, int out_size, void* d_ws, size_t ws_size,
                              hipStream_t stream) {
    const float* e  = (const float*)d_in[0];   // [1024,32,512] f32
    const float* wp = (const float*)d_in[1];   // scalar
    const float* bp = (const float*)d_in[2];   // scalar
    float* out = (float*)d_out;

    // Fast-path workspace layout (bytes):
    //   sumf 2097152 | ssqA 131072 | dgl 131072 | active 131072 |
    //   pmA 1048576 | c2A 4096 | count 4 | doneCnt 4
    const size_t NEED_FAST = 3543048ull;

    if (ws_size >= NEED_FAST) {
        char* base = (char*)d_ws;
        float*  sumf    = (float*) (base);
        float*  ssqA    = (float*) (base + 2097152ull);
        float*  dgl     = (float*) (base + 2228224ull);
        int*    active  = (int*)   (base + 2359296ull);
        float2* pmA     = (float2*)(base + 2490368ull);
        float*  c2A     = (float*) (base + 3538944ull);
        int*    count   = (int*)   (base + 3543040ull);
        int*    doneCnt = (int*)   (base + 3543044ull);

        prep_kernel<<<N_SPK, 256, 0, stream>>>(e, sumf, ssqA, dgl, c2A,
                                               wp, bp, out, count, doneCnt);
        select_kernel<<<NROWS / 256, 256, 0, stream>>>(ssqA, dgl, c2A,
                                                       wp, bp, count, active);
        active_kernel<<<512, 256, 0, stream>>>(e, sumf, dgl, count, active,
                                               wp, bp, pmA, doneCnt, out);
    } else {
        float* ws = (float*)d_ws;
        float* cent     = ws;
        float* nsq      = ws + 524288;
        float* partials = ws + 524288 + 32768;

        centroid_kernel<<<N_SPK * D_EMB / 256, 256, 0, stream>>>(e, cent);
        normsq_kernel<<<NROWS / 4, 256, 0, stream>>>(e, nsq);
        ge2e_main<<<NROWS / BR, 256, 0, stream>>>(e, cent, nsq, wp, bp, partials);
        reduce_kernel<<<1, 256, 0, stream>>>(partials, out);
    }
}

// Round 5
// 117.968 us; speedup vs baseline: 1.3779x; 1.0467x over previous
//
#include <hip/hip_runtime.h>

// Problem constants (fixed by the reference).
#define N_SPK 1024
#define M_UTT 32
#define D_EMB 512
#define NROWS (N_SPK * M_UTT)   // 32768

#define NEG_INF (-__builtin_inff())
#define MARGIN 25.0f   // skip row iff dgl - rowbound >= MARGIN (err < 1.4e-8/row)

using f32x4 = __attribute__((ext_vector_type(4))) float;

// ===========================================================================
// FAST PATH (round 15): prune-then-compute, 3 dispatches.
//
// R14 post-mortem: dispatch gaps ~= 0 (merge fusion bought 0.2us); the
// active phase scales with CONCURRENT BLOCK COUNT (R12: 10 blocks = 60us;
// R14: ~64 blocks = ~15us).  R15 refines the item decomposition one level:
// item = (slot, 64-speaker group), 64-thread blocks, 16 groups/slot ->
// ~160-320 working blocks (4x the cross-CU memory-level parallelism).
//
// Bit-exactness: one wave == exactly the old (chunk, wave) lane set, so the
// 64-lane butterflies are unchanged; pm16[slot][g16] == old red2[c][wv]
// with g16 = 4c+wv.  The last block (done-counter) replays the old
// per-chunk combine (groups 4c..4c+3) then the 4-chunk merge combine in
// the identical nesting -> absmax stays 0.0.
//
// XCD locality: blocks serving group g16 have blockIdx === g16 (mod 16),
// hence XCD = g16&7 fixed -> each group's 128KB sumf slice is re-read from
// ONE XCD's L2.
//
// Math unchanged from R10: dgl ~ 2641 +- 630 while every off-diag logit is
// bounded by |w|*||e||*max||c|| + b ~ 459 (Cauchy-Schwarz).  Rows with
// dgl - bound >= 25 nats contribute exactly-0 loss in the reference too.
// R11 kept: no init dispatch; c2A per-speaker array instead of atomicMax.
// ===========================================================================

// ---------------------------------------------------------------------------
// prep: one block per speaker n (32 rows x 512 dims).  Reads e ONCE.
//  - sumf[n*512+d] = sum_m e[n][m][d]      (fp32 speaker sum, 2 MB)
//  - ssqA[row]     = ||e_row||^2
//  - dgl[row]      = w*(e.sum + ||e||^2/31) + b   (exact fp32 diag logit)
//  - c2A[n]        = ||c_n||^2             (per-speaker, no atomics)
//  - block 0 zeroes out[0], *count, *doneCnt (replaces init dispatch)
// ---------------------------------------------------------------------------
__global__ __launch_bounds__(256)
void prep_kernel(const float* __restrict__ e,
                 float* __restrict__ sumf, float* __restrict__ ssqA,
                 float* __restrict__ dgl, float* __restrict__ c2A,
                 const float* __restrict__ wp, const float* __restrict__ bp,
                 float* __restrict__ out, int* __restrict__ count,
                 int* __restrict__ doneCnt) {
    __shared__ float csum[4][D_EMB];   // 8 KiB
    __shared__ float c2red[4];
    const int n = blockIdx.x;
    const int wv = threadIdx.x >> 6, l = threadIdx.x & 63;

    if (n == 0 && threadIdx.x == 0) { out[0] = 0.f; *count = 0; *doneCnt = 0; }

    float xs[8][8];     // retained row data (lane's 8 dims x 8 rows)
    float ssq[8];       // per-row ||e||^2 (wave-uniform after butterfly)
    float cacc[8];
#pragma unroll
    for (int j = 0; j < 8; ++j) cacc[j] = 0.f;

#pragma unroll
    for (int mi = 0; mi < 8; ++mi) {
        const int m = mi * 4 + wv;
        const size_t row = (size_t)n * M_UTT + m;
        const float* p = e + row * D_EMB + l * 8;
        float4 x0 = *(const float4*)p;
        float4 x1 = *(const float4*)(p + 4);
        xs[mi][0] = x0.x; xs[mi][1] = x0.y; xs[mi][2] = x0.z; xs[mi][3] = x0.w;
        xs[mi][4] = x1.x; xs[mi][5] = x1.y; xs[mi][6] = x1.z; xs[mi][7] = x1.w;
        float sq = 0.f;
#pragma unroll
        for (int j = 0; j < 8; ++j) {
            float x = xs[mi][j];
            cacc[j] += x;
            sq = __builtin_fmaf(x, x, sq);
        }
#pragma unroll
        for (int off = 32; off; off >>= 1) sq += __shfl_xor(sq, off);
        ssq[mi] = sq;
        if (l == 0) ssqA[row] = sq;
    }

#pragma unroll
    for (int j = 0; j < 8; ++j) csum[wv][l * 8 + j] = cacc[j];
    __syncthreads();
    float c2acc = 0.f;
    for (int d = threadIdx.x; d < D_EMB; d += 256) {
        float s = csum[0][d] + csum[1][d] + csum[2][d] + csum[3][d];
        csum[0][d] = s;                               // full speaker sum
        sumf[(size_t)n * D_EMB + d] = s;
        float c = s * (1.0f / M_UTT);
        c2acc = __builtin_fmaf(c, c, c2acc);
    }
#pragma unroll
    for (int off = 32; off; off >>= 1) c2acc += __shfl_xor(c2acc, off);
    if (l == 0) c2red[wv] = c2acc;
    __syncthreads();   // csum[0] full sums + c2red visible
    if (threadIdx.x == 0)
        c2A[n] = (c2red[0] + c2red[1]) + (c2red[2] + c2red[3]);

    // Exact fp32 diag: dgl[row] = w*(e.sum + ssq/31) + b.
    float sv[8];
#pragma unroll
    for (int j = 0; j < 8; ++j) sv[j] = csum[0][l * 8 + j];
    const float w = wp[0], bb = bp[0];
#pragma unroll
    for (int mi = 0; mi < 8; ++mi) {
        float dg = 0.f;
#pragma unroll
        for (int j = 0; j < 8; ++j) dg = __builtin_fmaf(xs[mi][j], sv[j], dg);
#pragma unroll
        for (int off = 32; off; off >>= 1) dg += __shfl_xor(dg, off);
        if (l == 0) {
            const size_t row = (size_t)n * M_UTT + mi * 4 + wv;
            dgl[row] = __builtin_fmaf(w, dg + ssq[mi] * (1.0f / 31.0f), bb);
        }
    }
}

// ---------------------------------------------------------------------------
// select: one thread per row.  Each block first max-reduces c2A (4 KB,
// L2-hot) to Cmax^2 — exact same max the old atomicMax produced (fmaxf is
// rounding-free, order-independent).  Row survives iff
// dgl - (|w|*||e||*Cmax + b) < MARGIN.  Survivors appended to active[]
// (device atomic; ~10-20 appends total).
// ---------------------------------------------------------------------------
__global__ __launch_bounds__(256)
void select_kernel(const float* __restrict__ ssqA, const float* __restrict__ dgl,
                   const float* __restrict__ c2A,
                   const float* __restrict__ wp, const float* __restrict__ bp,
                   int* __restrict__ count, int* __restrict__ active) {
    __shared__ float red[4];
    float m = 0.f;   // c2 > 0 always
#pragma unroll
    for (int i = 0; i < 4; ++i)
        m = fmaxf(m, c2A[threadIdx.x + i * 256]);
#pragma unroll
    for (int off = 32; off; off >>= 1) m = fmaxf(m, __shfl_xor(m, off));
    if ((threadIdx.x & 63) == 0) red[threadIdx.x >> 6] = m;
    __syncthreads();
    const float c2 = fmaxf(fmaxf(red[0], red[1]), fmaxf(red[2], red[3]));
    const float Cmax = __builtin_sqrtf(c2);

    const int row = blockIdx.x * 256 + threadIdx.x;
    const float bound = __builtin_fmaf(
        __builtin_fabsf(wp[0]) * __builtin_sqrtf(ssqA[row]), Cmax, bp[0]);
    if (dgl[row] - bound < MARGIN) {
        int slot = atomicAdd(count, 1);
        active[slot] = row;
    }
}

// ---------------------------------------------------------------------------
// active (fused merge): item = (slot, 64-speaker group g16).  ONE WAVE per
// block; lane t computes speaker j = g16*64 + t with the identical dot
// chain and the identical 64-lane butterfly as R11's wave (chunk=g16>>2,
// wv=g16&3).  Lane 0 release-stores the (max,sumexp) partial to
// pm16[slot*16+g16] and the block counts its items into doneCnt; the
// unique block crossing cnt*16 merges every slot with the identical old
// nesting (per-chunk 4-group combine, then 4-chunk combine) -> bit-exact.
// ---------------------------------------------------------------------------
__global__ __launch_bounds__(64)
void active_kernel(const float* __restrict__ e, const float* __restrict__ sumf,
                   const float* __restrict__ dgl,
                   const int* __restrict__ count, const int* __restrict__ active,
                   const float* __restrict__ wp, const float* __restrict__ bp,
                   float2* __restrict__ pm16, int* __restrict__ doneCnt,
                   float* __restrict__ out) {
    __shared__ float er[D_EMB];
    __shared__ int lastFlag;
    const int tid = threadIdx.x;   // 0..63
    const int cnt = *count;
    if (cnt == 0) return;          // out already 0 from prep
    const float w = wp[0], bb = bp[0];

    const int g16 = blockIdx.x & 15;          // 64-speaker group
    const int slot0 = blockIdx.x >> 4;
    const int gstride = gridDim.x >> 4;       // 64

    if (tid == 0) lastFlag = 0;
    int myItems = 0;

    for (int slot = slot0; slot < cnt; slot += gstride) {
        const int row = active[slot];
        __syncthreads();   // protect er (and lastFlag init, 1st iter)
#pragma unroll
        for (int i = 0; i < 8; ++i)
            er[tid + i * 64] = e[(size_t)row * D_EMB + tid + i * 64];
        __syncthreads();

        const int j = g16 * 64 + tid;         // speaker (column) index
        const float* sp = sumf + (size_t)j * D_EMB;
        float d0 = 0.f, d1 = 0.f, d2 = 0.f, d3 = 0.f;
        for (int k = 0; k < D_EMB; k += 4) {
            float4 s4 = *(const float4*)(sp + k);
            d0 = __builtin_fmaf(er[k + 0], s4.x, d0);
            d1 = __builtin_fmaf(er[k + 1], s4.y, d1);
            d2 = __builtin_fmaf(er[k + 2], s4.z, d2);
            d3 = __builtin_fmaf(er[k + 3], s4.w, d3);
        }
        const float dot = (d0 + d1) + (d2 + d3);
        float lg = __builtin_fmaf(w, dot * (1.0f / M_UTT), bb);
        if (j == (row >> 5)) lg = dgl[row];   // exact diag substitution

        float mx = lg;
#pragma unroll
        for (int off = 32; off; off >>= 1) mx = fmaxf(mx, __shfl_xor(mx, off));
        float ss = __expf(lg - mx);
#pragma unroll
        for (int off = 32; off; off >>= 1) ss += __shfl_xor(ss, off);
        if (tid == 0) {
            float2 v; v.x = mx; v.y = ss;
            __hip_atomic_store((unsigned long long*)&pm16[slot * 16 + g16],
                               __builtin_bit_cast(unsigned long long, v),
                               __ATOMIC_RELAXED, __HIP_MEMORY_SCOPE_AGENT);
        }
        ++myItems;
    }

    __syncthreads();
    if (tid == 0 && myItems > 0) {
        int old = __hip_atomic_fetch_add(doneCnt, myItems,
                                         __ATOMIC_ACQ_REL,
                                         __HIP_MEMORY_SCOPE_AGENT);
        if (old + myItems == cnt * 16) lastFlag = 1;   // unique crossing block
    }
    __syncthreads();

    if (lastFlag) {
        // Merge ALL slots with the identical old nesting:
        //   per chunk c: combine groups 4c..4c+3 (old red2[c][0..3] order),
        //   then the old merge_kernel 4-chunk combine.
        for (int slot = tid; slot < cnt; slot += 64) {
            float2 pm[4];
#pragma unroll
            for (int c = 0; c < 4; ++c) {
                float2 r0, r1, r2, r3;
                unsigned long long b0 = __hip_atomic_load(
                    (unsigned long long*)&pm16[slot * 16 + 4 * c + 0],
                    __ATOMIC_RELAXED, __HIP_MEMORY_SCOPE_AGENT);
                unsigned long long b1 = __hip_atomic_load(
                    (unsigned long long*)&pm16[slot * 16 + 4 * c + 1],
                    __ATOMIC_RELAXED, __HIP_MEMORY_SCOPE_AGENT);
                unsigned long long b2 = __hip_atomic_load(
                    (unsigned long long*)&pm16[slot * 16 + 4 * c + 2],
                    __ATOMIC_RELAXED, __HIP_MEMORY_SCOPE_AGENT);
                unsigned long long b3 = __hip_atomic_load(
                    (unsigned long long*)&pm16[slot * 16 + 4 * c + 3],
                    __ATOMIC_RELAXED, __HIP_MEMORY_SCOPE_AGENT);
                r0 = __builtin_bit_cast(float2, b0);
                r1 = __builtin_bit_cast(float2, b1);
                r2 = __builtin_bit_cast(float2, b2);
                r3 = __builtin_bit_cast(float2, b3);
                float M = fmaxf(fmaxf(r0.x, r1.x), fmaxf(r2.x, r3.x));
                float S = r0.y * __expf(r0.x - M)
                        + r1.y * __expf(r1.x - M)
                        + r2.y * __expf(r2.x - M)
                        + r3.y * __expf(r3.x - M);
                pm[c].x = M; pm[c].y = S;
            }
            float M = fmaxf(fmaxf(pm[0].x, pm[1].x), fmaxf(pm[2].x, pm[3].x));
            float S = pm[0].y * __expf(pm[0].x - M) + pm[1].y * __expf(pm[1].x - M)
                    + pm[2].y * __expf(pm[2].x - M) + pm[3].y * __expf(pm[3].x - M);
            float loss = M + __logf(S) - dgl[active[slot]];
            atomicAdd(out, loss * (1.0f / NROWS));
        }
    }
}

// ===========================================================================
// FALLBACK PATH (round-1 fp32 vector kernels) — used if ws_size is too small.
// ===========================================================================

__global__ void centroid_kernel(const float* __restrict__ e,
                                float* __restrict__ cent) {
    int gid = blockIdx.x * 256 + threadIdx.x;
    int n = gid >> 9;
    int d = gid & 511;
    const float* p = e + ((size_t)n * M_UTT) * D_EMB + d;
    float s = 0.f;
#pragma unroll
    for (int m = 0; m < M_UTT; ++m) s += p[(size_t)m * D_EMB];
    cent[gid] = s * (1.0f / M_UTT);
}

__global__ void normsq_kernel(const float* __restrict__ e,
                              float* __restrict__ nsq) {
    int wv = threadIdx.x >> 6;
    int lane = threadIdx.x & 63;
    int row = blockIdx.x * 4 + wv;
    const float* p = e + (size_t)row * D_EMB + lane;
    float s = 0.f;
#pragma unroll
    for (int j = 0; j < 8; ++j) { float x = p[j * 64]; s += x * x; }
#pragma unroll
    for (int off = 32; off; off >>= 1) s += __shfl_xor(s, off);
    if (lane == 0) nsq[row] = s;
}

#define BR 64
#define BC 128
#define BK 16
#define TR 4
#define TC 8

__global__ __launch_bounds__(256, 2)
void ge2e_main(const float* __restrict__ e, const float* __restrict__ cent,
               const float* __restrict__ nsq, const float* __restrict__ wp,
               const float* __restrict__ bp, float* __restrict__ partials) {
    __shared__ float As[BK][BR];
    __shared__ float Bs[BK][BC];
    __shared__ float diagLs[BR];
    __shared__ float red[16];

    const int tid = threadIdx.x;
    const int tx = tid & 15;
    const int ty = tid >> 4;
    const int blk = blockIdx.x;
    const int r0 = blk * BR;

    const float w = *wp;
    const float bb = *bp;

    float m_run[TR], s_run[TR];
#pragma unroll
    for (int i = 0; i < TR; ++i) { m_run[i] = NEG_INF; s_run[i] = 0.f; }

    const int a_row = tid >> 2;
    const int a_k   = (tid & 3) * 4;
    const int b_col = tid >> 1;
    const int b_k   = (tid & 1) * 8;

    for (int ct = 0; ct < N_SPK / BC; ++ct) {
        const int c0 = ct * BC;
        float acc[TR][TC];
#pragma unroll
        for (int i = 0; i < TR; ++i)
#pragma unroll
            for (int j = 0; j < TC; ++j) acc[i][j] = 0.f;

        for (int kk = 0; kk < D_EMB; kk += BK) {
            __syncthreads();
            {
                float4 av = *(const float4*)(e + (size_t)(r0 + a_row) * D_EMB + kk + a_k);
                As[a_k + 0][a_row] = av.x;
                As[a_k + 1][a_row] = av.y;
                As[a_k + 2][a_row] = av.z;
                As[a_k + 3][a_row] = av.w;
            }
            {
                const float* bp0 = cent + (size_t)(c0 + b_col) * D_EMB + kk + b_k;
                float4 bv0 = *(const float4*)(bp0);
                float4 bv1 = *(const float4*)(bp0 + 4);
                Bs[b_k + 0][b_col] = bv0.x;
                Bs[b_k + 1][b_col] = bv0.y;
                Bs[b_k + 2][b_col] = bv0.z;
                Bs[b_k + 3][b_col] = bv0.w;
                Bs[b_k + 4][b_col] = bv1.x;
                Bs[b_k + 5][b_col] = bv1.y;
                Bs[b_k + 6][b_col] = bv1.z;
                Bs[b_k + 7][b_col] = bv1.w;
            }
            __syncthreads();

#pragma unroll
            for (int k = 0; k < BK; ++k) {
                float4 a4 = *(const float4*)&As[k][ty * TR];
                float4 b4a = *(const float4*)&Bs[k][tx * TC];
                float4 b4b = *(const float4*)&Bs[k][tx * TC + 4];
                float av[TR] = {a4.x, a4.y, a4.z, a4.w};
                float bv[TC] = {b4a.x, b4a.y, b4a.z, b4a.w,
                                b4b.x, b4b.y, b4b.z, b4b.w};
#pragma unroll
                for (int i = 0; i < TR; ++i)
#pragma unroll
                    for (int j = 0; j < TC; ++j)
                        acc[i][j] = __builtin_fmaf(av[i], bv[j], acc[i][j]);
            }
        }

#pragma unroll
        for (int i = 0; i < TR; ++i) {
            const int grow = r0 + ty * TR + i;
            const int dcol = grow >> 5;
            float lv[TC];
#pragma unroll
            for (int j = 0; j < TC; ++j) {
                const int gcol = c0 + tx * TC + j;
                float v = acc[i][j];
                float lg;
                if (gcol == dcol) {
                    lg = __builtin_fmaf(w, __builtin_fmaf(32.0f, v,
                             (1.0f / 31.0f) * nsq[grow]), bb);
                    diagLs[ty * TR + i] = lg;
                } else {
                    lg = __builtin_fmaf(w, v, bb);
                }
                lv[j] = lg;
            }
            float mx = lv[0];
#pragma unroll
            for (int j = 1; j < TC; ++j) mx = fmaxf(mx, lv[j]);
#pragma unroll
            for (int off = 8; off; off >>= 1) mx = fmaxf(mx, __shfl_xor(mx, off));
            float ss = 0.f;
#pragma unroll
            for (int j = 0; j < TC; ++j) ss += __expf(lv[j] - mx);
#pragma unroll
            for (int off = 8; off; off >>= 1) ss += __shfl_xor(ss, off);
            float nm = fmaxf(m_run[i], mx);
            s_run[i] = s_run[i] * __expf(m_run[i] - nm) + ss * __expf(mx - nm);
            m_run[i] = nm;
        }
    }

    __syncthreads();
    if (tx == 0) {
        float part = 0.f;
#pragma unroll
        for (int i = 0; i < TR; ++i) {
            const int lr = ty * TR + i;
            part += m_run[i] + __logf(s_run[i]) - diagLs[lr];
        }
        red[ty] = part;
    }
    __syncthreads();
    if (tid == 0) {
        float t = 0.f;
#pragma unroll
        for (int i = 0; i < 16; ++i) t += red[i];
        partials[blk] = t;
    }
}

__global__ void reduce_kernel(const float* __restrict__ partials,
                              float* __restrict__ out) {
    __shared__ float red[4];
    int tid = threadIdx.x;
    float v = partials[tid] + partials[tid + 256];
#pragma unroll
    for (int off = 32; off; off >>= 1) v += __shfl_xor(v, off);
    if ((tid & 63) == 0) red[tid >> 6] = v;
    __syncthreads();
    if (tid == 0)
        out[0] = (red[0] + red[1] + red[2] + red[3]) * (1.0f / NROWS);
}

// ===========================================================================

extern "C" void kernel_launch(void* const* d_in, const int* in_sizes, int n_in,
                              void* d_out, int out_size, void* d_ws, size_t ws_size,
                              hipStream_t stream) {
    const float* e  = (const float*)d_in[0];   // [1024,32,512] f32
    const float* wp = (const float*)d_in[1];   // scalar
    const float* bp = (const float*)d_in[2];   // scalar
    float* out = (float*)d_out;

    // Fast-path workspace layout (bytes):
    //   sumf 2097152 | ssqA 131072 | dgl 131072 | active 131072 |
    //   pm16 4194304 (32768 slots x 16 x float2) | c2A 4096 | count 4 |
    //   doneCnt 4
    const size_t NEED_FAST = 6688776ull;

    if (ws_size >= NEED_FAST) {
        char* base = (char*)d_ws;
        float*  sumf    = (float*) (base);
        float*  ssqA    = (float*) (base + 2097152ull);
        float*  dgl     = (float*) (base + 2228224ull);
        int*    active  = (int*)   (base + 2359296ull);
        float2* pm16    = (float2*)(base + 2490368ull);
        float*  c2A     = (float*) (base + 6684672ull);
        int*    count   = (int*)   (base + 6688768ull);
        int*    doneCnt = (int*)   (base + 6688772ull);

        prep_kernel<<<N_SPK, 256, 0, stream>>>(e, sumf, ssqA, dgl, c2A,
                                               wp, bp, out, count, doneCnt);
        select_kernel<<<NROWS / 256, 256, 0, stream>>>(ssqA, dgl, c2A,
                                                       wp, bp, count, active);
        active_kernel<<<1024, 64, 0, stream>>>(e, sumf, dgl, count, active,
                                               wp, bp, pm16, doneCnt, out);
    } else {
        float* ws = (float*)d_ws;
        float* cent     = ws;
        float* nsq      = ws + 524288;
        float* partials = ws + 524288 + 32768;

        centroid_kernel<<<N_SPK * D_EMB / 256, 256, 0, stream>>>(e, cent);
        normsq_kernel<<<NROWS / 4, 256, 0, stream>>>(e, nsq);
        ge2e_main<<<NROWS / BR, 256, 0, stream>>>(e, cent, nsq, wp, bp, partials);
        reduce_kernel<<<1, 256, 0, stream>>>(partials, out);
    }
}